// Round 1
// baseline (184.619 us; speedup 1.0000x reference)
//
#include <hip/hip_runtime.h>
#include <hip/hip_bf16.h>

// Problem constants (from reference): B=1024 batch, L=256 latent, H=512 hidden,
// T=16 node types, N=128 nodes (num_nodes input is a fixed scalar = 128).
#define BB 1024
#define LL 256
#define HH 512
#define TT 16
#define NN 128

#define NODE_F4 (BB * NN * TT / 4)   // 524288 float4
#define EDGE_F4 (BB * NN * NN / 4)   // 4194304 float4

// ---------------------------------------------------------------------------
// K0: W_e1sum[k][j] = W_e1[k][j] + W_e1[k+512][j]   (folds cat(h,h) @ W_e1
// into h @ W_e1sum, halving GEMM2's K). 512*512 floats = 65536 float4.
__global__ __launch_bounds__(256) void k_sumw(const float* __restrict__ We1,
                                              float* __restrict__ Wsum) {
    int q = blockIdx.x * 256 + threadIdx.x;          // 0..65535
    const float4* a = (const float4*)We1;
    float4 t = a[q];
    float4 b = a[q + (HH * HH / 4)];                 // bottom half offset 65536 f4
    float4 r = make_float4(t.x + b.x, t.y + b.y, t.z + b.z, t.w + b.w);
    ((float4*)Wsum)[q] = r;
}

// ---------------------------------------------------------------------------
// Tiled fp32 GEMM + bias + relu:  out[M x HH] = relu(A[M x K] @ W[K x HH] + bias)
// Tile: 32 rows x 64 cols per block, 256 threads. A tile staged in LDS
// (32*K floats). Weights read column-tile-wise: each col-tile of W read once
// per 32-row block => total W traffic = (B/32) * W bytes (L2-resident).
// Thread t handles col = bx*64 + (t&63), rows g+4m (g = t>>6, m=0..7).
// Within a wave all lanes share g => LDS A reads are broadcast (conflict-free).
template <int K>
__global__ __launch_bounds__(256) void k_gemm_relu(const float* __restrict__ A,
                                                   const float* __restrict__ W,
                                                   const float* __restrict__ bias,
                                                   float* __restrict__ out) {
    __shared__ float As[32 * K];                     // K=256: 32KB, K=512: 64KB
    const int tid  = threadIdx.x;
    const int row0 = blockIdx.y * 32;
    const int col  = blockIdx.x * 64 + (tid & 63);
    const int g    = tid >> 6;

    // Stage contiguous 32 x K A-tile as float4s.
    const float4* Av  = (const float4*)(A + row0 * K);
    float4*       Asv = (float4*)As;
    #pragma unroll
    for (int s = 0; s < K / 32; ++s) {
        int u = tid + 256 * s;                       // 0 .. 8K-1 float4
        Asv[u] = Av[u];
    }
    __syncthreads();

    float acc[8] = {0.f, 0.f, 0.f, 0.f, 0.f, 0.f, 0.f, 0.f};
    for (int k4 = 0; k4 < K / 4; ++k4) {
        const int k = k4 * 4;
        float w0 = W[(k + 0) * HH + col];
        float w1 = W[(k + 1) * HH + col];
        float w2 = W[(k + 2) * HH + col];
        float w3 = W[(k + 3) * HH + col];
        #pragma unroll
        for (int m = 0; m < 8; ++m) {
            const int r = g + 4 * m;
            float4 a = *((const float4*)(As + r * K + k));  // ds_read_b128, broadcast
            acc[m] += a.x * w0 + a.y * w1 + a.z * w2 + a.w * w3;
        }
    }

    const float bb = bias[col];
    #pragma unroll
    for (int m = 0; m < 8; ++m) {
        const int r = g + 4 * m;
        out[(row0 + r) * HH + col] = fmaxf(acc[m] + bb, 0.f);
    }
}

// ---------------------------------------------------------------------------
// K3: per batch row b: node16[b][:] = h[b] @ W_node + b_node  (16 outs, K=512)
//     p[b] = sigmoid(e1[b] @ W_e2 + b_e2)                     (K=512 dot)
// One block (256 threads) per row.
__global__ __launch_bounds__(256) void k_head(const float* __restrict__ h,
                                              const float* __restrict__ e1,
                                              const float* __restrict__ Wn,
                                              const float* __restrict__ bn,
                                              const float* __restrict__ We2,
                                              const float* __restrict__ be2,
                                              float* __restrict__ node16,
                                              float* __restrict__ p) {
    const int b   = blockIdx.x;
    const int tid = threadIdx.x;
    __shared__ float hs[HH];
    __shared__ float red[256];

    hs[tid]       = h[b * HH + tid];
    hs[tid + 256] = h[b * HH + tid + 256];
    __syncthreads();

    // node16: 16 outputs x 16 partial-threads each
    const int o = tid & 15, part = tid >> 4;
    float s = 0.f;
    #pragma unroll 4
    for (int kk = 0; kk < 32; ++kk) {
        const int k = part * 32 + kk;
        s += hs[k] * Wn[k * TT + o];
    }
    red[tid] = s;
    __syncthreads();
    if (tid < 16) {
        float t = 0.f;
        #pragma unroll
        for (int q = 0; q < 16; ++q) t += red[q * 16 + tid];
        node16[b * TT + tid] = t + bn[tid];
    }
    __syncthreads();

    // p: 512-dot, 2 elements/thread, wave64 shuffle reduce + cross-wave LDS
    float s2 = e1[b * HH + tid] * We2[tid] + e1[b * HH + tid + 256] * We2[tid + 256];
    #pragma unroll
    for (int off = 32; off; off >>= 1) s2 += __shfl_down(s2, off);
    if ((tid & 63) == 0) red[tid >> 6] = s2;
    __syncthreads();
    if (tid == 0) {
        float t = red[0] + red[1] + red[2] + red[3] + be2[0];
        p[b] = 1.f / (1.f + __expf(-t));
    }
}

// ---------------------------------------------------------------------------
// K4: the 72 MiB broadcast write (the roofline term).
// out layout: [node_logits 1024x128x16][edge_probs 1024x128x128], fp32.
// node_logits[b,n,t] = node16[b][t];  edge_probs[b,i,j] = (j<i) ? p[b] : 0.
// One float4 store per thread, all indices power-of-two shifts/masks.
__global__ __launch_bounds__(256) void k_write(const float* __restrict__ node16,
                                               const float* __restrict__ p,
                                               float4* __restrict__ out) {
    const int q = blockIdx.x * 256 + threadIdx.x;
    if (q < NODE_F4) {
        const int b  = q >> 9;           // N*T/4 = 512 f4 per batch row
        const int t4 = q & 3;            // 16/4 = 4 f4 per node
        out[q] = ((const float4*)(node16 + b * TT))[t4];
    } else {
        const int e  = q - NODE_F4;
        const int b  = e >> 12;          // N*N/4 = 4096 f4 per batch row
        const int i  = (e >> 5) & 127;   // 128/4 = 32 f4 per i-row
        const int j0 = (e & 31) * 4;
        const float pv = p[b];
        float4 v;
        v.x = (j0 + 0 < i) ? pv : 0.f;
        v.y = (j0 + 1 < i) ? pv : 0.f;
        v.z = (j0 + 2 < i) ? pv : 0.f;
        v.w = (j0 + 3 < i) ? pv : 0.f;
        out[q] = v;
    }
}

// ---------------------------------------------------------------------------
extern "C" void kernel_launch(void* const* d_in, const int* in_sizes, int n_in,
                              void* d_out, int out_size, void* d_ws, size_t ws_size,
                              hipStream_t stream) {
    const float* z    = (const float*)d_in[0];
    // d_in[1] = num_nodes (int scalar) — fixed at 128, hard-coded as NN.
    const float* Wz   = (const float*)d_in[2];
    const float* bz   = (const float*)d_in[3];
    const float* Wn   = (const float*)d_in[4];
    const float* bn   = (const float*)d_in[5];
    const float* We1  = (const float*)d_in[6];
    const float* be1  = (const float*)d_in[7];
    const float* We2  = (const float*)d_in[8];
    const float* be2  = (const float*)d_in[9];
    float* out = (float*)d_out;

    // Workspace layout (floats): h | e1 | W_e1sum | node16 | p   (~5.3 MB)
    float* ws     = (float*)d_ws;
    float* h      = ws;                       // 1024*512
    float* e1     = h + BB * HH;              // 1024*512
    float* Wsum   = e1 + BB * HH;             // 512*512
    float* node16 = Wsum + HH * HH;           // 1024*16
    float* p      = node16 + BB * TT;         // 1024

    // K0: fold W_e1 halves (65536 f4 / 256 threads = 256 blocks)
    k_sumw<<<HH * HH / 4 / 256, 256, 0, stream>>>(We1, Wsum);

    // K1: h = relu(z @ W_z + b_z)   grid: 8 col-tiles x 32 row-tiles
    k_gemm_relu<LL><<<dim3(HH / 64, BB / 32), 256, 0, stream>>>(z, Wz, bz, h);

    // K2: e1 = relu(h @ W_e1sum + b_e1)
    k_gemm_relu<HH><<<dim3(HH / 64, BB / 32), 256, 0, stream>>>(h, Wsum, be1, e1);

    // K3: node16 + p heads
    k_head<<<BB, 256, 0, stream>>>(h, e1, Wn, bn, We2, be2, node16, p);

    // K4: broadcast-write the full output (exactly covers out_size/4 float4s)
    k_write<<<(NODE_F4 + EDGE_F4) / 256, 256, 0, stream>>>(node16, p, (float4*)out);

    (void)in_sizes; (void)n_in; (void)out_size; (void)ws_size;
}